// Round 10
// baseline (31.403 us; speedup 1.0000x reference)
//
#include <hip/hip_runtime.h>

// QuantumAttention: out[b,s,e] = sum_q q[b,s,q] * W_dec[e,q] + x[b,s,e]
//   angles = x @ W_enc^T, c = cos(angles)
//   q[0] = prod(c[1..7]); q[i] = prod(c[0..i])
//
// R10: copy-kernel-shaped persistent blocks. grid 1024, 16 tokens/block as
// 4 groups x 4 tokens; next group's x loads issue BEFORE this group's
// compute (continuous VMEM issue, no phase-locked bursts). Weights loaded
// once and pinned with empty asm("+v") so the allocator can't sink them
// into the loop (R6: VGPR=60 proved re-loading). launch_bounds(256,1)
// gives the allocator ~256 VGPR: no spill; 2 blocks/CU resident + 2
// queued per CU -> staggered block phases. R9's dedup combine kept
// (2 barriers/group, wave0-only cos/cumprod via DPP product-scan).

typedef float v2f __attribute__((ext_vector_type(2)));
typedef float v4f __attribute__((ext_vector_type(4)));

#define EDIM 1024
#define QDIM 8
#define NTOK 16384
#define BLOCK 256
#define G 4                        // tokens per group
#define ITERS 4                    // groups per block
#define GRID (NTOK / (G * ITERS))  // 1024

// v += dpp_move(v); bound_ctrl=true -> out-of-range lanes contribute 0
template<int CTRL>
__device__ __forceinline__ float dpp_add(float v) {
    int m = __builtin_amdgcn_update_dpp(0, __float_as_int(v), CTRL, 0xF, 0xF, true);
    return v + __int_as_float(m);
}

// 64-lane sum on the VALU pipe; result valid in lane 63 only.
__device__ __forceinline__ float wave_sum63(float v) {
    v = dpp_add<0x111>(v);   // row_shr:1
    v = dpp_add<0x112>(v);   // row_shr:2
    v = dpp_add<0x114>(v);   // row_shr:4
    v = dpp_add<0x118>(v);   // row_shr:8
    v = dpp_add<0x142>(v);   // row_bcast:15
    v = dpp_add<0x143>(v);   // row_bcast:31
    return v;
}

// inclusive product-scan step within 8-lane groups (guarded row_shr)
template<int K>
__device__ __forceinline__ float scan_mul_step(float p, int laneq) {
    int m = __builtin_amdgcn_update_dpp(0, __float_as_int(p), 0x110 | K, 0xF, 0xF, true);
    float tmul = (laneq >= K) ? __int_as_float(m) : 1.0f;
    return p * tmul;
}

__global__ __launch_bounds__(BLOCK, 1)
void qattn_kernel(const float* __restrict__ x,
                  const float* __restrict__ W_enc,   // [Q][E]
                  const float* __restrict__ W_dec,   // [E][Q]
                  float* __restrict__ out)
{
    __shared__ float red[G][4][QDIM];
    __shared__ float qv_s[G][QDIM];

    const int t    = threadIdx.x;
    const int lane = t & 63;
    const int wave = t >> 6;
    const int e0   = t * 4;
    const int tok0 = blockIdx.x * (G * ITERS);

    // ---- weights once, pinned so they can't be sunk into the loop ----
    v4f wenc[QDIM];
#pragma unroll
    for (int q = 0; q < QDIM; ++q)
        wenc[q] = *(const v4f*)(W_enc + q * EDIM + e0);
    v4f wdlo[4], wdhi[4];
#pragma unroll
    for (int j = 0; j < 4; ++j) {
        wdlo[j] = *(const v4f*)(W_dec + (e0 + j) * QDIM);
        wdhi[j] = *(const v4f*)(W_dec + (e0 + j) * QDIM + 4);
    }
#pragma unroll
    for (int q = 0; q < QDIM; ++q) asm volatile("" : "+v"(wenc[q]));
#pragma unroll
    for (int j = 0; j < 4; ++j) {
        asm volatile("" : "+v"(wdlo[j]));
        asm volatile("" : "+v"(wdhi[j]));
    }

    // ---- first group's x ----
    v4f xv[G];
#pragma unroll
    for (int i = 0; i < G; ++i)
        xv[i] = *(const v4f*)(x + (size_t)(tok0 + i) * EDIM + e0);

    for (int it = 0; it < ITERS; ++it) {
        // 1. issue next group's loads first (continuous VMEM stream)
        v4f xn[G];
        if (it + 1 < ITERS) {
#pragma unroll
            for (int i = 0; i < G; ++i)
                xn[i] = *(const v4f*)(x + (size_t)(tok0 + (it + 1) * G + i) * EDIM + e0);
        }

        // 2. encode + DPP reduce (pure VALU; prefetch in flight underneath)
        float ang[G][QDIM];
#pragma unroll
        for (int i = 0; i < G; ++i) {
            v2f x01 = (v2f){xv[i].x, xv[i].y};
            v2f x23 = (v2f){xv[i].z, xv[i].w};
#pragma unroll
            for (int q = 0; q < QDIM; ++q) {
                v2f acc = x01 * (v2f){wenc[q].x, wenc[q].y};
                acc = __builtin_elementwise_fma(x23, (v2f){wenc[q].z, wenc[q].w}, acc);
                ang[i][q] = acc.x + acc.y;
            }
        }
#pragma unroll
        for (int i = 0; i < G; ++i)
#pragma unroll
            for (int q = 0; q < QDIM; ++q)
                ang[i][q] = wave_sum63(ang[i][q]);

        // 3. publish wave partials, barrier
        if (lane == 63) {
#pragma unroll
            for (int i = 0; i < G; ++i) {
                *(v4f*)&red[i][wave][0] = (v4f){ang[i][0], ang[i][1], ang[i][2], ang[i][3]};
                *(v4f*)&red[i][wave][4] = (v4f){ang[i][4], ang[i][5], ang[i][6], ang[i][7]};
            }
        }
        __syncthreads();

        // 4. wave 0: combine + cos + cumprod scan (lanes 0..G*8-1), barrier
        if (wave == 0 && lane < G * QDIM) {
            const int tk = lane >> 3;
            const int q  = lane & 7;
            float s = red[tk][0][q] + red[tk][1][q] + red[tk][2][q] + red[tk][3][q];
            float c = __cosf(s);

            float p = c;                      // q -> c0*...*cq
            p = scan_mul_step<1>(p, q);
            p = scan_mul_step<2>(p, q);
            p = scan_mul_step<4>(p, q);

            float b = (q == 0) ? 1.0f : c;    // q=7 -> c1*...*c7
            b = scan_mul_step<1>(b, q);
            b = scan_mul_step<2>(b, q);
            b = scan_mul_step<4>(b, q);

            if (q > 0)  qv_s[tk][q] = p;
            if (q == 7) qv_s[tk][0] = b;
        }
        __syncthreads();

        // 5. decode + residual + nontemporal store
#pragma unroll
        for (int i = 0; i < G; ++i) {
            v4f qlo = *(const v4f*)&qv_s[i][0];
            v4f qhi = *(const v4f*)&qv_s[i][4];
            float oacc[4];
#pragma unroll
            for (int j = 0; j < 4; ++j) {
                v4f a = qlo * wdlo[j];
                a = __builtin_elementwise_fma(qhi, wdhi[j], a);
                v2f hh = (v2f){a.x, a.y} + (v2f){a.z, a.w};
                oacc[j] = hh.x + hh.y;
            }
            v4f o = xv[i] + (v4f){oacc[0], oacc[1], oacc[2], oacc[3]};
            __builtin_nontemporal_store(o, (v4f*)(out + (size_t)(tok0 + it * G + i) * EDIM + e0));
        }

        // 6. rotate prefetch
        if (it + 1 < ITERS) {
#pragma unroll
            for (int i = 0; i < G; ++i) xv[i] = xn[i];
        }
    }
}

extern "C" void kernel_launch(void* const* d_in, const int* in_sizes, int n_in,
                              void* d_out, int out_size, void* d_ws, size_t ws_size,
                              hipStream_t stream) {
    const float* x     = (const float*)d_in[0];
    const float* W_enc = (const float*)d_in[1];
    const float* W_dec = (const float*)d_in[2];
    float* out         = (float*)d_out;

    hipLaunchKernelGGL(qattn_kernel, dim3(GRID), dim3(BLOCK), 0, stream,
                       x, W_enc, W_dec, out);
}

// Round 11
// 30.963 us; speedup vs baseline: 1.0142x; 1.0142x over previous
//
#include <hip/hip_runtime.h>

// QuantumAttention: out[b,s,e] = sum_q q[b,s,q] * W_dec[e,q] + x[b,s,e]
//   angles = x @ W_enc^T, c = cos(angles)
//   q[0] = prod(c[1..7]); q[i] = prod(c[0..i])
//
// R11: async staging. Every prior fused variant drained the memory pipe at
// each __syncthreads (compiler emits s_waitcnt vmcnt(0) before s_barrier)
// and capped prefetch depth by VGPRs. Now:
//  - x staged via global_load_lds (16B) into a 2x16KB LDS double buffer;
//    each wave stages/reads ONLY its own quarter (wave-private -> no
//    barrier for staging, just counted vmcnt, never 0 in steady state).
//  - barriers for red/qv_s are raw s_barrier + lgkmcnt(0) only: loads and
//    stores stay in flight across group boundaries.
//  - weights in regs, DPP reduce, wave0-dedup cos/cumprod scan, NT stores.

typedef float v2f __attribute__((ext_vector_type(2)));
typedef float v4f __attribute__((ext_vector_type(4)));

#define EDIM 1024
#define QDIM 8
#define NTOK 16384
#define BLOCK 256
#define G 4                        // tokens per group
#define ITERS 4                    // groups per block
#define GRID (NTOK / (G * ITERS))  // 1024 -> 4 blocks/CU exactly

#define GLOAD_LDS(gsrc, ldst)                                                  \
    __builtin_amdgcn_global_load_lds(                                          \
        (const __attribute__((address_space(1))) void*)(gsrc),                 \
        (__attribute__((address_space(3))) void*)(ldst), 16, 0, 0)

// v += dpp_move(v); bound_ctrl=true -> out-of-range lanes contribute 0
template<int CTRL>
__device__ __forceinline__ float dpp_add(float v) {
    int m = __builtin_amdgcn_update_dpp(0, __float_as_int(v), CTRL, 0xF, 0xF, true);
    return v + __int_as_float(m);
}

// 64-lane sum on the VALU pipe; result valid in lane 63 only.
__device__ __forceinline__ float wave_sum63(float v) {
    v = dpp_add<0x111>(v);   // row_shr:1
    v = dpp_add<0x112>(v);   // row_shr:2
    v = dpp_add<0x114>(v);   // row_shr:4
    v = dpp_add<0x118>(v);   // row_shr:8
    v = dpp_add<0x142>(v);   // row_bcast:15
    v = dpp_add<0x143>(v);   // row_bcast:31
    return v;
}

// inclusive product-scan step within 8-lane groups (guarded row_shr)
template<int K>
__device__ __forceinline__ float scan_mul_step(float p, int laneq) {
    int m = __builtin_amdgcn_update_dpp(0, __float_as_int(p), 0x110 | K, 0xF, 0xF, true);
    float tmul = (laneq >= K) ? __int_as_float(m) : 1.0f;
    return p * tmul;
}

__global__ __launch_bounds__(BLOCK, 4)
void qattn_kernel(const float* __restrict__ x,
                  const float* __restrict__ W_enc,   // [Q][E]
                  const float* __restrict__ W_dec,   // [E][Q]
                  float* __restrict__ out)
{
    __shared__ float xbuf[2][G][EDIM];   // 32 KB double buffer
    __shared__ float red[G][4][QDIM];
    __shared__ float qv_s[G][QDIM];

    const int t    = threadIdx.x;
    const int lane = t & 63;
    const int wave = t >> 6;
    const int e0   = t * 4;              // = wave*256 + lane*4
    const int tok0 = blockIdx.x * (G * ITERS);

    // ---- weights into registers (L2-resident, 16 loads) ----
    v4f wenc[QDIM];
#pragma unroll
    for (int q = 0; q < QDIM; ++q)
        wenc[q] = *(const v4f*)(W_enc + q * EDIM + e0);
    v4f wdlo[4], wdhi[4];
#pragma unroll
    for (int j = 0; j < 4; ++j) {
        wdlo[j] = *(const v4f*)(W_dec + (e0 + j) * QDIM);
        wdhi[j] = *(const v4f*)(W_dec + (e0 + j) * QDIM + 4);
    }

    // ---- prologue: stage group 0 (each wave stages its own 1KB quarter) ----
#pragma unroll
    for (int i = 0; i < G; ++i) {
        const float* src = x + (size_t)(tok0 + i) * EDIM + wave * 256 + lane * 4;
        GLOAD_LDS(src, &xbuf[0][i][wave * 256]);
    }

#pragma unroll
    for (int it = 0; it < ITERS; ++it) {
        const int cb = it & 1;

        // 1. stage next group (fire-and-forget, zero VGPR cost)
        if (it + 1 < ITERS) {
#pragma unroll
            for (int i = 0; i < G; ++i) {
                const float* src = x + (size_t)(tok0 + (it + 1) * G + i) * EDIM
                                   + wave * 256 + lane * 4;
                GLOAD_LDS(src, &xbuf[cb ^ 1][i][wave * 256]);
            }
        }

        // 2. counted wait for CURRENT buffer only (never vmcnt(0) mid-loop):
        //    it==0:  allow stage(1)              -> vmcnt(4)
        //    middle: allow stage(next)+stores(-1)-> vmcnt(8)
        //    last:   allow stores(prev)          -> vmcnt(4)
        if (it == 0)                asm volatile("s_waitcnt vmcnt(4)" ::: "memory");
        else if (it + 1 < ITERS)    asm volatile("s_waitcnt vmcnt(8)" ::: "memory");
        else                        asm volatile("s_waitcnt vmcnt(4)" ::: "memory");
        __builtin_amdgcn_sched_barrier(0);

        // 3. read own x quarter from LDS (linear, its own staged bytes)
        v4f xv[G];
#pragma unroll
        for (int i = 0; i < G; ++i)
            xv[i] = *(const v4f*)&xbuf[cb][i][e0];

        // 4. encode + DPP reduce in 2 halves of 2 tokens (reg pressure)
#pragma unroll
        for (int h = 0; h < 2; ++h) {
            float ang[2][QDIM];
#pragma unroll
            for (int i = 0; i < 2; ++i) {
                const int ii = h * 2 + i;
                v2f x01 = (v2f){xv[ii].x, xv[ii].y};
                v2f x23 = (v2f){xv[ii].z, xv[ii].w};
#pragma unroll
                for (int q = 0; q < QDIM; ++q) {
                    v2f acc = x01 * (v2f){wenc[q].x, wenc[q].y};
                    acc = __builtin_elementwise_fma(x23, (v2f){wenc[q].z, wenc[q].w}, acc);
                    ang[i][q] = acc.x + acc.y;
                }
            }
#pragma unroll
            for (int i = 0; i < 2; ++i)
#pragma unroll
                for (int q = 0; q < QDIM; ++q)
                    ang[i][q] = wave_sum63(ang[i][q]);

            if (lane == 63) {
#pragma unroll
                for (int i = 0; i < 2; ++i) {
                    *(v4f*)&red[h * 2 + i][wave][0] =
                        (v4f){ang[i][0], ang[i][1], ang[i][2], ang[i][3]};
                    *(v4f*)&red[h * 2 + i][wave][4] =
                        (v4f){ang[i][4], ang[i][5], ang[i][6], ang[i][7]};
                }
            }
        }

        // 5. barrier WITHOUT vmcnt drain (LDS deps only)
        asm volatile("s_waitcnt lgkmcnt(0)" ::: "memory");
        __builtin_amdgcn_s_barrier();
        __builtin_amdgcn_sched_barrier(0);

        // 6. wave 0: combine + cos + cumprod scan (lanes 0..G*8-1)
        if (wave == 0 && lane < G * QDIM) {
            const int tk = lane >> 3;
            const int q  = lane & 7;
            float s = red[tk][0][q] + red[tk][1][q] + red[tk][2][q] + red[tk][3][q];
            float c = __cosf(s);

            float p = c;                      // q -> c0*...*cq
            p = scan_mul_step<1>(p, q);
            p = scan_mul_step<2>(p, q);
            p = scan_mul_step<4>(p, q);

            float b = (q == 0) ? 1.0f : c;    // q=7 -> c1*...*c7
            b = scan_mul_step<1>(b, q);
            b = scan_mul_step<2>(b, q);
            b = scan_mul_step<4>(b, q);

            if (q > 0)  qv_s[tk][q] = p;
            if (q == 7) qv_s[tk][0] = b;
        }

        // 7. barrier WITHOUT vmcnt drain
        asm volatile("s_waitcnt lgkmcnt(0)" ::: "memory");
        __builtin_amdgcn_s_barrier();
        __builtin_amdgcn_sched_barrier(0);

        // 8. decode + residual + NT store (stores fly across groups)
#pragma unroll
        for (int i = 0; i < G; ++i) {
            v4f qlo = *(const v4f*)&qv_s[i][0];
            v4f qhi = *(const v4f*)&qv_s[i][4];
            float oacc[4];
#pragma unroll
            for (int j = 0; j < 4; ++j) {
                v4f a = qlo * wdlo[j];
                a = __builtin_elementwise_fma(qhi, wdhi[j], a);
                v2f hh = (v2f){a.x, a.y} + (v2f){a.z, a.w};
                oacc[j] = hh.x + hh.y;
            }
            v4f o = xv[i] + (v4f){oacc[0], oacc[1], oacc[2], oacc[3]};
            __builtin_nontemporal_store(o, (v4f*)(out + (size_t)(tok0 + it * G + i) * EDIM + e0));
        }
    }
}

extern "C" void kernel_launch(void* const* d_in, const int* in_sizes, int n_in,
                              void* d_out, int out_size, void* d_ws, size_t ws_size,
                              hipStream_t stream) {
    const float* x     = (const float*)d_in[0];
    const float* W_enc = (const float*)d_in[1];
    const float* W_dec = (const float*)d_in[2];
    float* out         = (float*)d_out;

    hipLaunchKernelGGL(qattn_kernel, dim3(GRID), dim3(BLOCK), 0, stream,
                       x, W_enc, W_dec, out);
}